// Round 19
// baseline (284.738 us; speedup 1.0000x reference)
//
#include <hip/hip_runtime.h>
#include <hip/hip_cooperative_groups.h>

namespace cg = cooperative_groups;

namespace {
constexpr int kV = 256, kO = 128, kE = 1024, kD = 128;
constexpr int kN = kV * kO;    // 32768 nodes
constexpr int kVE = kV * kE;   // 262144 edges
constexpr float kEps = 1e-5f;
}

typedef __attribute__((ext_vector_type(8))) short bf16x8;
typedef __attribute__((ext_vector_type(8))) unsigned short u16x8;
typedef __attribute__((ext_vector_type(4))) float f32x4;

__device__ __forceinline__ unsigned short f2bf(float x) {
  unsigned u = __float_as_uint(x);
  return (unsigned short)((u + 0x7FFFu + ((u >> 16) & 1u)) >> 16);
}
__device__ __forceinline__ float bf2f(unsigned short h) {
  return __uint_as_float((unsigned)h << 16);
}

// ---- K1 (merged init): blocks 0..255 adjacency+stats; 256..287 weight split
__global__ __launch_bounds__(256) void k_init(
    const unsigned int* __restrict__ ew, const float* __restrict__ X,
    int* __restrict__ cnt_s, int* __restrict__ cnt_o,
    unsigned short* __restrict__ Au16, float* __restrict__ p1,
    const float* __restrict__ w1u0, const float* __restrict__ w2u0,
    const float* __restrict__ w1u1, const float* __restrict__ w2u1,
    unsigned short* __restrict__ img0, unsigned short* __restrict__ w2img0,
    unsigned short* __restrict__ img1, unsigned short* __restrict__ w2img1) {
  __shared__ int cnt[kO * kO];
  __shared__ int degS[kO], degO[kO];
  __shared__ int anyodd;
  int t = threadIdx.x;
  if (blockIdx.x >= 256) {
    const float* w1s[2] = {w1u0, w1u1};
    const float* w2s[2] = {w2u0, w2u1};
    unsigned short* img[2] = {img0, img1};
    unsigned short* w2i[2] = {w2img0, w2img1};
    int i0 = (blockIdx.x - 256) * 256 + t, stride = 32 * 256;
#pragma unroll
    for (int u = 0; u < 2; ++u) {
      for (int i = i0; i < kD * 2 * kD; i += stride) {
        int j = i >> 8, k = i & 255;
        int m = k >> 7, kk = k & 127;
        int pos = j * 128 + (kk ^ ((j & 7) << 3));
        float x = w1s[u][i];
        unsigned short hb = f2bf(x);
        img[u][(m * 2 + 0) * 16384 + pos] = hb;
        img[u][(m * 2 + 1) * 16384 + pos] = f2bf(x - bf2f(hb));
      }
      for (int i = i0; i < kD * kD; i += stride) {
        int j = i >> 7, kk = i & 127;
        int pos = j * 128 + (kk ^ ((j & 7) << 3));
        float x = w2s[u][i];
        unsigned short hb = f2bf(x);
        w2i[u][pos] = hb;
        w2i[u][16384 + pos] = f2bf(x - bf2f(hb));
      }
    }
    return;
  }
  int v = blockIdx.x;
  if (t == 0) anyodd = 0;
  for (int i = t; i < kO * kO; i += 256) cnt[i] = 0;
  __syncthreads();
  int base = v * 3072, loc = 0;
  for (int i = t; i < 3072; i += 256) {
    int g = base + i;
    if ((g & 1) && ew[g] != 0u) loc = 1;
  }
  if (loc) atomicOr(&anyodd, 1);
  __syncthreads();
  bool is64 = (anyodd == 0);
  for (int e = t; e < kE; e += 256) {
    long long eb = (long long)(v * kE + e) * 3;
    unsigned s, o;
    if (is64) { s = ew[2 * eb]; o = ew[2 * (eb + 2)]; }
    else      { s = ew[eb];     o = ew[eb + 2]; }
    s &= 127u; o &= 127u;
    atomicAdd(&cnt[s * kO + o], 1);
  }
  __syncthreads();
  unsigned int* A32 = (unsigned int*)(Au16 + (size_t)v * 16384);
  for (int i2 = t; i2 < 8192; i2 += 256) {
    int i = 2 * i2;
    int row = i >> 7, k = i & 127, kg = k >> 3;
    int j = row * 128 + ((kg ^ (row & 7)) << 3) + (k & 7);
    unsigned lo = (unsigned)cnt[i], hi = (unsigned)cnt[i + 1];
    A32[j >> 1] = lo | (hi << 16);
  }
  if (t < kO) {
    int s = 0;
    for (int c = 0; c < kO; ++c) s += cnt[t * kO + ((c + t) & 127)];
    degS[t] = s;
    cnt_s[v * kO + t] = s;
  } else {
    int tc = t - kO;
    int s = 0;
    for (int r = 0; r < kO; ++r) s += cnt[((r + tc) & 127) * kO + tc];
    degO[tc] = s;
    cnt_o[v * kO + tc] = s;
  }
  __syncthreads();
  int dq = (t & 31) * 4, rg = t >> 5;
  float acc[4][4];
#pragma unroll
  for (int a = 0; a < 4; ++a)
#pragma unroll
    for (int j = 0; j < 4; ++j) acc[a][j] = 0.f;
  for (int k = 0; k < 16; ++k) {
    int row = rg + k * 8;
    float4 xv = *(const float4*)(X + ((size_t)v * kO + row) * kD + dq);
    float wsv = (float)degS[row], wov = (float)degO[row];
    float xs[4] = {xv.x, xv.y, xv.z, xv.w};
#pragma unroll
    for (int j = 0; j < 4; ++j) {
      acc[0][j] += wsv * xs[j];
      acc[1][j] += wsv * xs[j] * xs[j];
      acc[2][j] += wov * xs[j];
      acc[3][j] += wov * xs[j] * xs[j];
    }
  }
  float* red = (float*)cnt;
  for (int st = 0; st < 4; ++st) {
    __syncthreads();
#pragma unroll
    for (int j = 0; j < 4; ++j) red[rg * 128 + dq + j] = acc[st][j];
    __syncthreads();
    if (t < 128) {
      float s = 0.f;
#pragma unroll
      for (int g = 0; g < 8; ++g) s += red[g * 128 + t];
      p1[((size_t)v * 4 + st) * 128 + t] = s;
    }
  }
}

// ---- K3: finalize BN1 coeffs — 256 blocks (one per column), 256 partials
__global__ __launch_bounds__(256) void k_fin1(
    const float* __restrict__ p1, const float* __restrict__ g1,
    const float* __restrict__ b1, float* __restrict__ coef) {
  __shared__ double sS[256], sQ[256];
  int c = blockIdx.x, t = threadIdx.x;
  int half = c >> 7, d = c & 127;
  double S = (double)p1[((size_t)t * 4 + half * 2 + 0) * 128 + d];
  double Q = (double)p1[((size_t)t * 4 + half * 2 + 1) * 128 + d];
  sS[t] = S; sQ[t] = Q;
  __syncthreads();
  for (int s = 128; s > 0; s >>= 1) {
    if (t < s) { sS[t] += sS[t + s]; sQ[t] += sQ[t + s]; }
    __syncthreads();
  }
  if (t == 0) {
    double m = sS[0] / (double)kVE;
    double var = sQ[0] / (double)kVE - m * m;
    float a = g1[c] / sqrtf((float)var + kEps);
    float beta = b1[c] - (float)m * a;
    coef[half * 256 + d] = a;
    coef[half * 256 + 128 + d] = beta;
  }
}

// ---- K_UNIT: cooperative per-unit kernel. 256 blocks x 512 threads
// (1 block/CU, co-resident). Part 1 = verified fused1 body; pooled kept
// in LDS (f32 swizzled tile in Wl[2..3]); p2 partials -> global.
// grid.sync(). Part 2 = W2 async-stage (Wl[0..1]) overlapped with
// redundant per-block f64 reduction p2 -> coef2 (LDS cf). Part 3 =
// verified W2 GEMM body reading pooled from LDS.
template <int STATS>
__global__ __launch_bounds__(512, 2) void k_unit(
    const float* __restrict__ X,
    const unsigned short* __restrict__ w1img,
    const unsigned short* __restrict__ w2img,
    const float* __restrict__ coef1, const unsigned short* __restrict__ Au16,
    const int* __restrict__ cnt_s, const int* __restrict__ cnt_o,
    const float* __restrict__ lb1, const float* __restrict__ g2,
    const float* __restrict__ b2, const float* __restrict__ bias2,
    const float* __restrict__ resid,
    float* __restrict__ p2, float* __restrict__ Y, float* __restrict__ p1out) {
  __shared__ __align__(16) unsigned short Wl[4][16384];  // 128 KiB
  __shared__ double scd[2][512];                          // 8 KiB
  __shared__ float cf[2][128];                            // 1 KiB
  int t = threadIdx.x, v = blockIdx.x;
  int lane = t & 63, wid = t >> 6;  // 8 waves, 16 rows each
  int wr = wid * 16, lrow = lane & 15, lkc = lane >> 4;
  int arow = wr + lrow;
  // ---- Part 1: stage W1 image (async) ----
#pragma unroll
  for (int a = 0; a < 4; ++a)
#pragma unroll
    for (int i = 0; i < 4; ++i)
      __builtin_amdgcn_global_load_lds(
          (const unsigned int*)((const char*)(w1img + a * 16384) +
                                wid * 4096 + i * 1024 + lane * 16),
          (unsigned int*)((char*)Wl[a] + wid * 4096 + i * 1024), 16, 0, 0);
  u16x8 au[4];
#pragma unroll
  for (int ks = 0; ks < 4; ++ks) {
    int kg = ks * 4 + lkc;
    au[ks] = *(const u16x8*)(Au16 + (size_t)v * 16384 + arow * 128 +
                             ((kg ^ (arow & 7)) << 3));
  }
  bf16x8 hsH[4], hsL[4], hoH[4], hoL[4];
#pragma unroll
  for (int ks = 0; ks < 4; ++ks) {
    int kb = ks * 32 + lkc * 8;
    float4 x0 = *(const float4*)(X + ((size_t)v * kO + arow) * kD + kb);
    float4 x1 = *(const float4*)(X + ((size_t)v * kO + arow) * kD + kb + 4);
    float4 aS0 = *(const float4*)(coef1 + kb),       aS1 = *(const float4*)(coef1 + kb + 4);
    float4 bS0 = *(const float4*)(coef1 + 128 + kb), bS1 = *(const float4*)(coef1 + 128 + kb + 4);
    float4 aO0 = *(const float4*)(coef1 + 256 + kb), aO1 = *(const float4*)(coef1 + 256 + kb + 4);
    float4 bO0 = *(const float4*)(coef1 + 384 + kb), bO1 = *(const float4*)(coef1 + 384 + kb + 4);
    float xs[8] = {x0.x, x0.y, x0.z, x0.w, x1.x, x1.y, x1.z, x1.w};
    float as[8] = {aS0.x, aS0.y, aS0.z, aS0.w, aS1.x, aS1.y, aS1.z, aS1.w};
    float bs[8] = {bS0.x, bS0.y, bS0.z, bS0.w, bS1.x, bS1.y, bS1.z, bS1.w};
    float ao[8] = {aO0.x, aO0.y, aO0.z, aO0.w, aO1.x, aO1.y, aO1.z, aO1.w};
    float bo[8] = {bO0.x, bO0.y, bO0.z, bO0.w, bO1.x, bO1.y, bO1.z, bO1.w};
#pragma unroll
    for (int e = 0; e < 8; ++e) {
      float hs = fmaxf(as[e] * xs[e] + bs[e], 0.f);
      float ho = fmaxf(ao[e] * xs[e] + bo[e], 0.f);
      unsigned short h1 = f2bf(hs);
      hsH[ks][e] = (short)h1;
      hsL[ks][e] = (short)f2bf(hs - bf2f(h1));
      unsigned short h2 = f2bf(ho);
      hoH[ks][e] = (short)h2;
      hoL[ks][e] = (short)f2bf(ho - bf2f(h2));
    }
  }
  __syncthreads();  // drain W1 staging
  f32x4 accS[8], accO[8];
#pragma unroll
  for (int j = 0; j < 8; ++j) {
    accS[j] = (f32x4){0.f, 0.f, 0.f, 0.f};
    accO[j] = (f32x4){0.f, 0.f, 0.f, 0.f};
  }
#pragma unroll
  for (int ks = 0; ks < 4; ++ks) {
    int kb = ks * 32 + lkc * 8;
#pragma unroll
    for (int jg = 0; jg < 8; ++jg) {
      int j = jg * 16 + lrow;
      int idx = j * 128 + (kb ^ ((j & 7) << 3));
      bf16x8 bsh = *(const bf16x8*)(&Wl[0][idx]);
      bf16x8 bsl = *(const bf16x8*)(&Wl[1][idx]);
      bf16x8 boh = *(const bf16x8*)(&Wl[2][idx]);
      bf16x8 bol = *(const bf16x8*)(&Wl[3][idx]);
      accS[jg] = __builtin_amdgcn_mfma_f32_16x16x32_bf16(hsH[ks], bsh, accS[jg], 0, 0, 0);
      accS[jg] = __builtin_amdgcn_mfma_f32_16x16x32_bf16(hsH[ks], bsl, accS[jg], 0, 0, 0);
      accS[jg] = __builtin_amdgcn_mfma_f32_16x16x32_bf16(hsL[ks], bsh, accS[jg], 0, 0, 0);
      accO[jg] = __builtin_amdgcn_mfma_f32_16x16x32_bf16(hoH[ks], boh, accO[jg], 0, 0, 0);
      accO[jg] = __builtin_amdgcn_mfma_f32_16x16x32_bf16(hoH[ks], bol, accO[jg], 0, 0, 0);
      accO[jg] = __builtin_amdgcn_mfma_f32_16x16x32_bf16(hoL[ks], boh, accO[jg], 0, 0, 0);
    }
  }
  __syncthreads();  // W1 consumed
  // transpose yo -> yoT in Wl[0..1]
#pragma unroll
  for (int jg = 0; jg < 8; ++jg) {
    int d = jg * 16 + lrow;
#pragma unroll
    for (int q = 0; q < 4; ++q) {
      int o = wr + lkc * 4 + q;
      int addr = d * 128 + (o ^ ((d & 7) << 3));
      float vv = accO[jg][q];
      unsigned short h = f2bf(vv);
      Wl[0][addr] = h;
      Wl[1][addr] = f2bf(vv - bf2f(h));
    }
  }
  __syncthreads();
  // pool GEMM: A (regs) x yoT (LDS)
  f32x4 accP[8];
#pragma unroll
  for (int j = 0; j < 8; ++j) accP[j] = (f32x4){0.f, 0.f, 0.f, 0.f};
#pragma unroll
  for (int ks = 0; ks < 4; ++ks) {
    int kb = ks * 32 + lkc * 8;
    bf16x8 pah, pal;
#pragma unroll
    for (int e = 0; e < 8; ++e) {
      float c = (float)au[ks][e];
      unsigned short hb = f2bf(c);
      pah[e] = (short)hb;
      pal[e] = (short)f2bf(c - bf2f(hb));
    }
#pragma unroll
    for (int jg = 0; jg < 8; ++jg) {
      int d = jg * 16 + lrow;
      int qi = d * 128 + (kb ^ ((d & 7) << 3));
      bf16x8 qh = *(const bf16x8*)(&Wl[0][qi]), ql = *(const bf16x8*)(&Wl[1][qi]);
      accP[jg] = __builtin_amdgcn_mfma_f32_16x16x32_bf16(pah, qh, accP[jg], 0, 0, 0);
      accP[jg] = __builtin_amdgcn_mfma_f32_16x16x32_bf16(pah, ql, accP[jg], 0, 0, 0);
      accP[jg] = __builtin_amdgcn_mfma_f32_16x16x32_bf16(pal, qh, accP[jg], 0, 0, 0);
    }
  }
  __syncthreads();  // yoT consumed; Wl[0] free for reduction scratch
  // phase E: pooled -> LDS tile (Wl[2..3], f32, col^((row&7)<<2) swizzle)
  float* plds = (float*)Wl[2];
  float* red  = (float*)Wl[0];
  float lb[8];
#pragma unroll
  for (int jg = 0; jg < 8; ++jg) lb[jg] = lb1[jg * 16 + lrow];
  float sm[8], sq[8];
#pragma unroll
  for (int jg = 0; jg < 8; ++jg) { sm[jg] = 0.f; sq[jg] = 0.f; }
#pragma unroll
  for (int q = 0; q < 4; ++q) {
    int row = wr + lkc * 4 + q;
    size_t n = (size_t)v * kO + row;
    int cnt = cnt_s[n];
    float inv = (cnt > 0) ? 1.f / (float)cnt : 0.f;
#pragma unroll
    for (int jg = 0; jg < 8; ++jg) {
      int col = jg * 16 + lrow;
      float pv = 0.f;
      if (cnt > 0) pv = accS[jg][q] + lb[jg] + accP[jg][q] * inv;
      plds[row * 128 + (col ^ ((row & 7) << 2))] = pv;
      sm[jg] += pv; sq[jg] += pv * pv;
    }
  }
  int slot = wid * 4 + lkc;  // 0..31
#pragma unroll
  for (int jg = 0; jg < 8; ++jg) red[slot * 128 + jg * 16 + lrow] = sm[jg];
  __syncthreads();
  if (t < 128) {
    float s = 0.f;
#pragma unroll
    for (int g = 0; g < 32; ++g) s += red[g * 128 + t];
    p2[((size_t)v * 2 + 0) * 128 + t] = s;
  }
  __syncthreads();
#pragma unroll
  for (int jg = 0; jg < 8; ++jg) red[slot * 128 + jg * 16 + lrow] = sq[jg];
  __syncthreads();
  if (t < 128) {
    float s = 0.f;
#pragma unroll
    for (int g = 0; g < 32; ++g) s += red[g * 128 + t];
    p2[((size_t)v * 2 + 1) * 128 + t] = s;
  }
  __threadfence();
  cg::this_grid().sync();
  // ---- Part 2: stage W2 (async, Wl[0..1]) + redundant coef2 reduction ----
#pragma unroll
  for (int a = 0; a < 2; ++a)
#pragma unroll
    for (int i = 0; i < 4; ++i)
      __builtin_amdgcn_global_load_lds(
          (const unsigned int*)((const char*)(w2img + a * 16384) +
                                wid * 4096 + i * 1024 + lane * 16),
          (unsigned int*)((char*)Wl[a] + wid * 4096 + i * 1024), 16, 0, 0);
  {
    int d = t & 127, g = t >> 7;
    double S = 0.0, Q = 0.0;
    for (int vv = g * 64; vv < g * 64 + 64; ++vv) {
      S += (double)p2[((size_t)vv * 2 + 0) * 128 + d];
      Q += (double)p2[((size_t)vv * 2 + 1) * 128 + d];
    }
    scd[0][t] = S; scd[1][t] = Q;
  }
  __syncthreads();
  if (t < 128) {
    double St = scd[0][t] + scd[0][128 + t] + scd[0][256 + t] + scd[0][384 + t];
    double Qt = scd[1][t] + scd[1][128 + t] + scd[1][256 + t] + scd[1][384 + t];
    double m = St / (double)kN, var = Qt / (double)kN - m * m;
    float a2 = g2[t] / sqrtf((float)var + kEps);
    cf[0][t] = a2;
    cf[1][t] = b2[t] - (float)m * a2;
  }
  __syncthreads();  // cf ready; W2 staging drained
  // ---- Part 3: transform pooled (LDS) -> frags; MFMA vs W2 (LDS) ----
  int sw = (arow & 7) << 2;
  bf16x8 ahH[4], ahL[4];
#pragma unroll
  for (int ks = 0; ks < 4; ++ks) {
    int kb = ks * 32 + lkc * 8;
    float4 p0 = *(const float4*)&plds[arow * 128 + (kb ^ sw)];
    float4 p1v = *(const float4*)&plds[arow * 128 + ((kb + 4) ^ sw)];
    float ps[8] = {p0.x, p0.y, p0.z, p0.w, p1v.x, p1v.y, p1v.z, p1v.w};
#pragma unroll
    for (int e = 0; e < 8; ++e) {
      float h = fmaxf(cf[0][kb + e] * ps[e] + cf[1][kb + e], 0.f);
      unsigned short hb = f2bf(h);
      ahH[ks][e] = (short)hb;
      ahL[ks][e] = (short)f2bf(h - bf2f(hb));
    }
  }
  f32x4 acc[8];
#pragma unroll
  for (int j = 0; j < 8; ++j) acc[j] = (f32x4){0.f, 0.f, 0.f, 0.f};
#pragma unroll
  for (int ks = 0; ks < 4; ++ks) {
    int kb = ks * 32 + lkc * 8;
#pragma unroll
    for (int jg = 0; jg < 8; ++jg) {
      int j = jg * 16 + lrow;
      int idx = j * 128 + (kb ^ ((j & 7) << 3));
      bf16x8 bh = *(const bf16x8*)(&Wl[0][idx]);
      bf16x8 bl = *(const bf16x8*)(&Wl[1][idx]);
      acc[jg] = __builtin_amdgcn_mfma_f32_16x16x32_bf16(ahH[ks], bh, acc[jg], 0, 0, 0);
      acc[jg] = __builtin_amdgcn_mfma_f32_16x16x32_bf16(ahH[ks], bl, acc[jg], 0, 0, 0);
      acc[jg] = __builtin_amdgcn_mfma_f32_16x16x32_bf16(ahL[ks], bh, acc[jg], 0, 0, 0);
    }
  }
  float s0[8], s1[8], s2[8], s3[8];
  if (STATS) {
#pragma unroll
    for (int jg = 0; jg < 8; ++jg) { s0[jg] = 0.f; s1[jg] = 0.f; s2[jg] = 0.f; s3[jg] = 0.f; }
  }
  float wsr[4], wor[4];
  if (STATS) {
#pragma unroll
    for (int q = 0; q < 4; ++q) {
      int n = v * kO + wr + lkc * 4 + q;
      wsr[q] = (float)cnt_s[n]; wor[q] = (float)cnt_o[n];
    }
  }
#pragma unroll
  for (int jg = 0; jg < 8; ++jg) {
    int col = jg * 16 + lrow;
    float bcol = bias2[col];
#pragma unroll
    for (int q = 0; q < 4; ++q) {
      int row = wr + lkc * 4 + q;
      size_t n = (size_t)v * kO + row;
      float vv = acc[jg][q] + bcol;
      if (resid) vv += resid[n * kD + col];
      Y[n * kD + col] = vv;
      if (STATS) {
        s0[jg] += wsr[q] * vv; s1[jg] += wsr[q] * vv * vv;
        s2[jg] += wor[q] * vv; s3[jg] += wor[q] * vv * vv;
      }
    }
  }
  if (STATS) {
    __syncthreads();  // W2 consumed; reuse Wl[0..1] as red [4][32][128] f32
    float* red4 = (float*)Wl[0];
#pragma unroll
    for (int jg = 0; jg < 8; ++jg) {
      int col = jg * 16 + lrow;
      red4[0 * 4096 + slot * 128 + col] = s0[jg];
      red4[1 * 4096 + slot * 128 + col] = s1[jg];
      red4[2 * 4096 + slot * 128 + col] = s2[jg];
      red4[3 * 4096 + slot * 128 + col] = s3[jg];
    }
    __syncthreads();
    if (t < 128) {
#pragma unroll
      for (int st = 0; st < 4; ++st) {
        float s = 0.f;
#pragma unroll
        for (int g = 0; g < 32; ++g) s += red4[st * 4096 + g * 128 + t];
        p1out[((size_t)v * 4 + st) * 128 + t] = s;
      }
    }
  }
}

extern "C" void kernel_launch(void* const* d_in, const int* in_sizes, int n_in,
                              void* d_out, int out_size, void* d_ws, size_t ws_size,
                              hipStream_t stream) {
  (void)in_sizes; (void)n_in; (void)out_size; (void)ws_size;
  const float* obj = (const float*)d_in[0];
  const unsigned int* ew = (const unsigned int*)d_in[1];
  const float* prm[2][8];
  for (int u = 0; u < 2; ++u)
    for (int p = 0; p < 8; ++p) prm[u][p] = (const float*)d_in[2 + u * 8 + p];
  // prm[u]: 0=g1 1=b1 2=W1 3=lb1 4=g2 5=b2 6=W2 7=lb2

  char* ws = (char*)d_ws;
  size_t off = 0;
  auto carve = [&](size_t bytes) -> char* {
    char* p = ws + off;
    off = (off + bytes + 255) & ~(size_t)255;
    return p;
  };
  int* cnt_s = (int*)carve((size_t)kN * 4);
  int* cnt_o = (int*)carve((size_t)kN * 4);
  unsigned short* Au16 = (unsigned short*)carve((size_t)kV * 16384 * 2);
  float* p1 = (float*)carve((size_t)256 * 4 * 128 * 4);
  float* p2 = (float*)carve((size_t)kV * 2 * 128 * 4);
  float* coef1 = (float*)carve(512 * 4);
  unsigned short *w1img[2], *w2img[2];
  for (int u = 0; u < 2; ++u) {
    w1img[u] = (unsigned short*)carve((size_t)4 * 16384 * 2);  // 128 KB
    w2img[u] = (unsigned short*)carve((size_t)2 * 16384 * 2);  // 64 KB
  }
  float* x2 = (float*)carve((size_t)kN * kD * 4);
  float* outp = (float*)d_out;

  k_init<<<288, 256, 0, stream>>>(ew, obj, cnt_s, cnt_o, Au16, p1,
                                  prm[0][2], prm[0][6], prm[1][2], prm[1][6],
                                  w1img[0], w2img[0], w1img[1], w2img[1]);

  // ---- unit 0 (cooperative) ----
  k_fin1<<<256, 256, 0, stream>>>(p1, prm[0][0], prm[0][1], coef1);
  {
    const float* X = obj;
    const unsigned short *wi = w1img[0], *w2i = w2img[0];
    const float *c1 = coef1;
    const unsigned short* Au = Au16;
    const int *cs = cnt_s, *co = cnt_o;
    const float *l1 = prm[0][3], *g2p = prm[0][4], *b2p = prm[0][5], *bi2 = prm[0][7];
    const float* rs = nullptr;
    float *p2p = p2, *Yp = x2, *p1p = p1;
    void* args[] = {(void*)&X, (void*)&wi, (void*)&w2i, (void*)&c1, (void*)&Au,
                    (void*)&cs, (void*)&co, (void*)&l1, (void*)&g2p, (void*)&b2p,
                    (void*)&bi2, (void*)&rs, (void*)&p2p, (void*)&Yp, (void*)&p1p};
    hipLaunchCooperativeKernel((const void*)k_unit<1>, dim3(kV), dim3(512),
                               args, 0, stream);
  }
  // ---- unit 1 (cooperative) ----
  k_fin1<<<256, 256, 0, stream>>>(p1, prm[1][0], prm[1][1], coef1);
  {
    const float* X = x2;
    const unsigned short *wi = w1img[1], *w2i = w2img[1];
    const float *c1 = coef1;
    const unsigned short* Au = Au16;
    const int *cs = cnt_s, *co = cnt_o;
    const float *l1 = prm[1][3], *g2p = prm[1][4], *b2p = prm[1][5], *bi2 = prm[1][7];
    const float* rs = obj;
    float *p2p = p2, *Yp = outp, *p1p = p1;
    void* args[] = {(void*)&X, (void*)&wi, (void*)&w2i, (void*)&c1, (void*)&Au,
                    (void*)&cs, (void*)&co, (void*)&l1, (void*)&g2p, (void*)&b2p,
                    (void*)&bi2, (void*)&rs, (void*)&p2p, (void*)&Yp, (void*)&p1p};
    hipLaunchCooperativeKernel((const void*)k_unit<0>, dim3(kV), dim3(512),
                               args, 0, stream);
  }
}

// Round 20
// 284.457 us; speedup vs baseline: 1.0010x; 1.0010x over previous
//
#include <hip/hip_runtime.h>
#include <hip/hip_cooperative_groups.h>

namespace cg = cooperative_groups;

namespace {
constexpr int kV = 256, kO = 128, kE = 1024, kD = 128;
constexpr int kN = kV * kO;    // 32768 nodes
constexpr int kVE = kV * kE;   // 262144 edges
constexpr float kEps = 1e-5f;
}

typedef __attribute__((ext_vector_type(8))) short bf16x8;
typedef __attribute__((ext_vector_type(8))) unsigned short u16x8;
typedef __attribute__((ext_vector_type(4))) float f32x4;

__device__ __forceinline__ unsigned short f2bf(float x) {
  unsigned u = __float_as_uint(x);
  return (unsigned short)((u + 0x7FFFu + ((u >> 16) & 1u)) >> 16);
}
__device__ __forceinline__ float bf2f(unsigned short h) {
  return __uint_as_float((unsigned)h << 16);
}

// ---- K1 (merged init): blocks 0..255 adjacency+stats; 256..287 weight split
__global__ __launch_bounds__(256) void k_init(
    const unsigned int* __restrict__ ew, const float* __restrict__ X,
    int* __restrict__ cnt_s, int* __restrict__ cnt_o,
    unsigned short* __restrict__ Au16, float* __restrict__ p1,
    const float* __restrict__ w1u0, const float* __restrict__ w2u0,
    const float* __restrict__ w1u1, const float* __restrict__ w2u1,
    unsigned short* __restrict__ img0, unsigned short* __restrict__ w2img0,
    unsigned short* __restrict__ img1, unsigned short* __restrict__ w2img1) {
  __shared__ int cnt[kO * kO];
  __shared__ int degS[kO], degO[kO];
  __shared__ int anyodd;
  int t = threadIdx.x;
  if (blockIdx.x >= 256) {
    const float* w1s[2] = {w1u0, w1u1};
    const float* w2s[2] = {w2u0, w2u1};
    unsigned short* img[2] = {img0, img1};
    unsigned short* w2i[2] = {w2img0, w2img1};
    int i0 = (blockIdx.x - 256) * 256 + t, stride = 32 * 256;
#pragma unroll
    for (int u = 0; u < 2; ++u) {
      for (int i = i0; i < kD * 2 * kD; i += stride) {
        int j = i >> 8, k = i & 255;
        int m = k >> 7, kk = k & 127;
        int pos = j * 128 + (kk ^ ((j & 7) << 3));
        float x = w1s[u][i];
        unsigned short hb = f2bf(x);
        img[u][(m * 2 + 0) * 16384 + pos] = hb;
        img[u][(m * 2 + 1) * 16384 + pos] = f2bf(x - bf2f(hb));
      }
      for (int i = i0; i < kD * kD; i += stride) {
        int j = i >> 7, kk = i & 127;
        int pos = j * 128 + (kk ^ ((j & 7) << 3));
        float x = w2s[u][i];
        unsigned short hb = f2bf(x);
        w2i[u][pos] = hb;
        w2i[u][16384 + pos] = f2bf(x - bf2f(hb));
      }
    }
    return;
  }
  int v = blockIdx.x;
  if (t == 0) anyodd = 0;
  for (int i = t; i < kO * kO; i += 256) cnt[i] = 0;
  __syncthreads();
  int base = v * 3072, loc = 0;
  for (int i = t; i < 3072; i += 256) {
    int g = base + i;
    if ((g & 1) && ew[g] != 0u) loc = 1;
  }
  if (loc) atomicOr(&anyodd, 1);
  __syncthreads();
  bool is64 = (anyodd == 0);
  for (int e = t; e < kE; e += 256) {
    long long eb = (long long)(v * kE + e) * 3;
    unsigned s, o;
    if (is64) { s = ew[2 * eb]; o = ew[2 * (eb + 2)]; }
    else      { s = ew[eb];     o = ew[eb + 2]; }
    s &= 127u; o &= 127u;
    atomicAdd(&cnt[s * kO + o], 1);
  }
  __syncthreads();
  unsigned int* A32 = (unsigned int*)(Au16 + (size_t)v * 16384);
  for (int i2 = t; i2 < 8192; i2 += 256) {
    int i = 2 * i2;
    int row = i >> 7, k = i & 127, kg = k >> 3;
    int j = row * 128 + ((kg ^ (row & 7)) << 3) + (k & 7);
    unsigned lo = (unsigned)cnt[i], hi = (unsigned)cnt[i + 1];
    A32[j >> 1] = lo | (hi << 16);
  }
  if (t < kO) {
    int s = 0;
    for (int c = 0; c < kO; ++c) s += cnt[t * kO + ((c + t) & 127)];
    degS[t] = s;
    cnt_s[v * kO + t] = s;
  } else {
    int tc = t - kO;
    int s = 0;
    for (int r = 0; r < kO; ++r) s += cnt[((r + tc) & 127) * kO + tc];
    degO[tc] = s;
    cnt_o[v * kO + tc] = s;
  }
  __syncthreads();
  int dq = (t & 31) * 4, rg = t >> 5;
  float acc[4][4];
#pragma unroll
  for (int a = 0; a < 4; ++a)
#pragma unroll
    for (int j = 0; j < 4; ++j) acc[a][j] = 0.f;
  for (int k = 0; k < 16; ++k) {
    int row = rg + k * 8;
    float4 xv = *(const float4*)(X + ((size_t)v * kO + row) * kD + dq);
    float wsv = (float)degS[row], wov = (float)degO[row];
    float xs[4] = {xv.x, xv.y, xv.z, xv.w};
#pragma unroll
    for (int j = 0; j < 4; ++j) {
      acc[0][j] += wsv * xs[j];
      acc[1][j] += wsv * xs[j] * xs[j];
      acc[2][j] += wov * xs[j];
      acc[3][j] += wov * xs[j] * xs[j];
    }
  }
  float* red = (float*)cnt;
  for (int st = 0; st < 4; ++st) {
    __syncthreads();
#pragma unroll
    for (int j = 0; j < 4; ++j) red[rg * 128 + dq + j] = acc[st][j];
    __syncthreads();
    if (t < 128) {
      float s = 0.f;
#pragma unroll
      for (int g = 0; g < 8; ++g) s += red[g * 128 + t];
      p1[((size_t)v * 4 + st) * 128 + t] = s;
    }
  }
}

// ---- K3: finalize BN1 coeffs — 256 blocks (one per column), 256 partials
__global__ __launch_bounds__(256) void k_fin1(
    const float* __restrict__ p1, const float* __restrict__ g1,
    const float* __restrict__ b1, float* __restrict__ coef) {
  __shared__ double sS[256], sQ[256];
  int c = blockIdx.x, t = threadIdx.x;
  int half = c >> 7, d = c & 127;
  double S = (double)p1[((size_t)t * 4 + half * 2 + 0) * 128 + d];
  double Q = (double)p1[((size_t)t * 4 + half * 2 + 1) * 128 + d];
  sS[t] = S; sQ[t] = Q;
  __syncthreads();
  for (int s = 128; s > 0; s >>= 1) {
    if (t < s) { sS[t] += sS[t + s]; sQ[t] += sQ[t + s]; }
    __syncthreads();
  }
  if (t == 0) {
    double m = sS[0] / (double)kVE;
    double var = sQ[0] / (double)kVE - m * m;
    float a = g1[c] / sqrtf((float)var + kEps);
    float beta = b1[c] - (float)m * a;
    coef[half * 256 + d] = a;
    coef[half * 256 + 128 + d] = beta;
  }
}

// ---- K_UNIT: cooperative per-unit kernel. 256 blocks x 512 threads
// (1 block/CU, co-resident). Part 1 = verified fused1 body; pooled kept
// in LDS (f32 swizzled tile in Wl[2..3]); p2 partials -> global.
// grid.sync(). Part 2 = W2 async-stage (Wl[0..1]) overlapped with
// redundant per-block f64 reduction p2 -> coef2 (LDS cf). Part 3 =
// verified W2 GEMM body reading pooled from LDS.
template <int STATS>
__global__ __launch_bounds__(512, 2) void k_unit(
    const float* __restrict__ X,
    const unsigned short* __restrict__ w1img,
    const unsigned short* __restrict__ w2img,
    const float* __restrict__ coef1, const unsigned short* __restrict__ Au16,
    const int* __restrict__ cnt_s, const int* __restrict__ cnt_o,
    const float* __restrict__ lb1, const float* __restrict__ g2,
    const float* __restrict__ b2, const float* __restrict__ bias2,
    const float* __restrict__ resid,
    float* __restrict__ p2, float* __restrict__ Y, float* __restrict__ p1out) {
  __shared__ __align__(16) unsigned short Wl[4][16384];  // 128 KiB
  __shared__ double scd[2][512];                          // 8 KiB
  __shared__ float cf[2][128];                            // 1 KiB
  int t = threadIdx.x, v = blockIdx.x;
  int lane = t & 63, wid = t >> 6;  // 8 waves, 16 rows each
  int wr = wid * 16, lrow = lane & 15, lkc = lane >> 4;
  int arow = wr + lrow;
  // ---- Part 1: stage W1 image (async) ----
#pragma unroll
  for (int a = 0; a < 4; ++a)
#pragma unroll
    for (int i = 0; i < 4; ++i)
      __builtin_amdgcn_global_load_lds(
          (const unsigned int*)((const char*)(w1img + a * 16384) +
                                wid * 4096 + i * 1024 + lane * 16),
          (unsigned int*)((char*)Wl[a] + wid * 4096 + i * 1024), 16, 0, 0);
  u16x8 au[4];
#pragma unroll
  for (int ks = 0; ks < 4; ++ks) {
    int kg = ks * 4 + lkc;
    au[ks] = *(const u16x8*)(Au16 + (size_t)v * 16384 + arow * 128 +
                             ((kg ^ (arow & 7)) << 3));
  }
  bf16x8 hsH[4], hsL[4], hoH[4], hoL[4];
#pragma unroll
  for (int ks = 0; ks < 4; ++ks) {
    int kb = ks * 32 + lkc * 8;
    float4 x0 = *(const float4*)(X + ((size_t)v * kO + arow) * kD + kb);
    float4 x1 = *(const float4*)(X + ((size_t)v * kO + arow) * kD + kb + 4);
    float4 aS0 = *(const float4*)(coef1 + kb),       aS1 = *(const float4*)(coef1 + kb + 4);
    float4 bS0 = *(const float4*)(coef1 + 128 + kb), bS1 = *(const float4*)(coef1 + 128 + kb + 4);
    float4 aO0 = *(const float4*)(coef1 + 256 + kb), aO1 = *(const float4*)(coef1 + 256 + kb + 4);
    float4 bO0 = *(const float4*)(coef1 + 384 + kb), bO1 = *(const float4*)(coef1 + 384 + kb + 4);
    float xs[8] = {x0.x, x0.y, x0.z, x0.w, x1.x, x1.y, x1.z, x1.w};
    float as[8] = {aS0.x, aS0.y, aS0.z, aS0.w, aS1.x, aS1.y, aS1.z, aS1.w};
    float bs[8] = {bS0.x, bS0.y, bS0.z, bS0.w, bS1.x, bS1.y, bS1.z, bS1.w};
    float ao[8] = {aO0.x, aO0.y, aO0.z, aO0.w, aO1.x, aO1.y, aO1.z, aO1.w};
    float bo[8] = {bO0.x, bO0.y, bO0.z, bO0.w, bO1.x, bO1.y, bO1.z, bO1.w};
#pragma unroll
    for (int e = 0; e < 8; ++e) {
      float hs = fmaxf(as[e] * xs[e] + bs[e], 0.f);
      float ho = fmaxf(ao[e] * xs[e] + bo[e], 0.f);
      unsigned short h1 = f2bf(hs);
      hsH[ks][e] = (short)h1;
      hsL[ks][e] = (short)f2bf(hs - bf2f(h1));
      unsigned short h2 = f2bf(ho);
      hoH[ks][e] = (short)h2;
      hoL[ks][e] = (short)f2bf(ho - bf2f(h2));
    }
  }
  __syncthreads();  // drain W1 staging
  f32x4 accS[8], accO[8];
#pragma unroll
  for (int j = 0; j < 8; ++j) {
    accS[j] = (f32x4){0.f, 0.f, 0.f, 0.f};
    accO[j] = (f32x4){0.f, 0.f, 0.f, 0.f};
  }
#pragma unroll
  for (int ks = 0; ks < 4; ++ks) {
    int kb = ks * 32 + lkc * 8;
#pragma unroll
    for (int jg = 0; jg < 8; ++jg) {
      int j = jg * 16 + lrow;
      int idx = j * 128 + (kb ^ ((j & 7) << 3));
      bf16x8 bsh = *(const bf16x8*)(&Wl[0][idx]);
      bf16x8 bsl = *(const bf16x8*)(&Wl[1][idx]);
      bf16x8 boh = *(const bf16x8*)(&Wl[2][idx]);
      bf16x8 bol = *(const bf16x8*)(&Wl[3][idx]);
      accS[jg] = __builtin_amdgcn_mfma_f32_16x16x32_bf16(hsH[ks], bsh, accS[jg], 0, 0, 0);
      accS[jg] = __builtin_amdgcn_mfma_f32_16x16x32_bf16(hsH[ks], bsl, accS[jg], 0, 0, 0);
      accS[jg] = __builtin_amdgcn_mfma_f32_16x16x32_bf16(hsL[ks], bsh, accS[jg], 0, 0, 0);
      accO[jg] = __builtin_amdgcn_mfma_f32_16x16x32_bf16(hoH[ks], boh, accO[jg], 0, 0, 0);
      accO[jg] = __builtin_amdgcn_mfma_f32_16x16x32_bf16(hoH[ks], bol, accO[jg], 0, 0, 0);
      accO[jg] = __builtin_amdgcn_mfma_f32_16x16x32_bf16(hoL[ks], boh, accO[jg], 0, 0, 0);
    }
  }
  __syncthreads();  // W1 consumed
  // transpose yo -> yoT in Wl[0..1]
#pragma unroll
  for (int jg = 0; jg < 8; ++jg) {
    int d = jg * 16 + lrow;
#pragma unroll
    for (int q = 0; q < 4; ++q) {
      int o = wr + lkc * 4 + q;
      int addr = d * 128 + (o ^ ((d & 7) << 3));
      float vv = accO[jg][q];
      unsigned short h = f2bf(vv);
      Wl[0][addr] = h;
      Wl[1][addr] = f2bf(vv - bf2f(h));
    }
  }
  __syncthreads();
  // pool GEMM: A (regs) x yoT (LDS)
  f32x4 accP[8];
#pragma unroll
  for (int j = 0; j < 8; ++j) accP[j] = (f32x4){0.f, 0.f, 0.f, 0.f};
#pragma unroll
  for (int ks = 0; ks < 4; ++ks) {
    int kb = ks * 32 + lkc * 8;
    bf16x8 pah, pal;
#pragma unroll
    for (int e = 0; e < 8; ++e) {
      float c = (float)au[ks][e];
      unsigned short hb = f2bf(c);
      pah[e] = (short)hb;
      pal[e] = (short)f2bf(c - bf2f(hb));
    }
#pragma unroll
    for (int jg = 0; jg < 8; ++jg) {
      int d = jg * 16 + lrow;
      int qi = d * 128 + (kb ^ ((d & 7) << 3));
      bf16x8 qh = *(const bf16x8*)(&Wl[0][qi]), ql = *(const bf16x8*)(&Wl[1][qi]);
      accP[jg] = __builtin_amdgcn_mfma_f32_16x16x32_bf16(pah, qh, accP[jg], 0, 0, 0);
      accP[jg] = __builtin_amdgcn_mfma_f32_16x16x32_bf16(pah, ql, accP[jg], 0, 0, 0);
      accP[jg] = __builtin_amdgcn_mfma_f32_16x16x32_bf16(pal, qh, accP[jg], 0, 0, 0);
    }
  }
  __syncthreads();  // yoT consumed; Wl[0] free for reduction scratch
  // phase E: pooled -> LDS tile (Wl[2..3], f32, col^((row&7)<<2) swizzle)
  float* plds = (float*)Wl[2];
  float* red  = (float*)Wl[0];
  float lb[8];
#pragma unroll
  for (int jg = 0; jg < 8; ++jg) lb[jg] = lb1[jg * 16 + lrow];
  float sm[8], sq[8];
#pragma unroll
  for (int jg = 0; jg < 8; ++jg) { sm[jg] = 0.f; sq[jg] = 0.f; }
#pragma unroll
  for (int q = 0; q < 4; ++q) {
    int row = wr + lkc * 4 + q;
    size_t n = (size_t)v * kO + row;
    int cnt = cnt_s[n];
    float inv = (cnt > 0) ? 1.f / (float)cnt : 0.f;
#pragma unroll
    for (int jg = 0; jg < 8; ++jg) {
      int col = jg * 16 + lrow;
      float pv = 0.f;
      if (cnt > 0) pv = accS[jg][q] + lb[jg] + accP[jg][q] * inv;
      plds[row * 128 + (col ^ ((row & 7) << 2))] = pv;
      sm[jg] += pv; sq[jg] += pv * pv;
    }
  }
  int slot = wid * 4 + lkc;  // 0..31
#pragma unroll
  for (int jg = 0; jg < 8; ++jg) red[slot * 128 + jg * 16 + lrow] = sm[jg];
  __syncthreads();
  if (t < 128) {
    float s = 0.f;
#pragma unroll
    for (int g = 0; g < 32; ++g) s += red[g * 128 + t];
    p2[((size_t)v * 2 + 0) * 128 + t] = s;
  }
  __syncthreads();
#pragma unroll
  for (int jg = 0; jg < 8; ++jg) red[slot * 128 + jg * 16 + lrow] = sq[jg];
  __syncthreads();
  if (t < 128) {
    float s = 0.f;
#pragma unroll
    for (int g = 0; g < 32; ++g) s += red[g * 128 + t];
    p2[((size_t)v * 2 + 1) * 128 + t] = s;
  }
  __threadfence();
  cg::this_grid().sync();
  // ---- Part 2: stage W2 (async, Wl[0..1]) + redundant coef2 reduction ----
#pragma unroll
  for (int a = 0; a < 2; ++a)
#pragma unroll
    for (int i = 0; i < 4; ++i)
      __builtin_amdgcn_global_load_lds(
          (const unsigned int*)((const char*)(w2img + a * 16384) +
                                wid * 4096 + i * 1024 + lane * 16),
          (unsigned int*)((char*)Wl[a] + wid * 4096 + i * 1024), 16, 0, 0);
  {
    int d = t & 127, g = t >> 7;
    double S = 0.0, Q = 0.0;
    for (int vv = g * 64; vv < g * 64 + 64; ++vv) {
      S += (double)p2[((size_t)vv * 2 + 0) * 128 + d];
      Q += (double)p2[((size_t)vv * 2 + 1) * 128 + d];
    }
    scd[0][t] = S; scd[1][t] = Q;
  }
  __syncthreads();
  if (t < 128) {
    double St = scd[0][t] + scd[0][128 + t] + scd[0][256 + t] + scd[0][384 + t];
    double Qt = scd[1][t] + scd[1][128 + t] + scd[1][256 + t] + scd[1][384 + t];
    double m = St / (double)kN, var = Qt / (double)kN - m * m;
    float a2 = g2[t] / sqrtf((float)var + kEps);
    cf[0][t] = a2;
    cf[1][t] = b2[t] - (float)m * a2;
  }
  __syncthreads();  // cf ready; W2 staging drained
  // ---- Part 3: transform pooled (LDS) -> frags; MFMA vs W2 (LDS) ----
  int sw = (arow & 7) << 2;
  bf16x8 ahH[4], ahL[4];
#pragma unroll
  for (int ks = 0; ks < 4; ++ks) {
    int kb = ks * 32 + lkc * 8;
    float4 p0 = *(const float4*)&plds[arow * 128 + (kb ^ sw)];
    float4 p1v = *(const float4*)&plds[arow * 128 + ((kb + 4) ^ sw)];
    float ps[8] = {p0.x, p0.y, p0.z, p0.w, p1v.x, p1v.y, p1v.z, p1v.w};
#pragma unroll
    for (int e = 0; e < 8; ++e) {
      float h = fmaxf(cf[0][kb + e] * ps[e] + cf[1][kb + e], 0.f);
      unsigned short hb = f2bf(h);
      ahH[ks][e] = (short)hb;
      ahL[ks][e] = (short)f2bf(h - bf2f(hb));
    }
  }
  f32x4 acc[8];
#pragma unroll
  for (int j = 0; j < 8; ++j) acc[j] = (f32x4){0.f, 0.f, 0.f, 0.f};
#pragma unroll
  for (int ks = 0; ks < 4; ++ks) {
    int kb = ks * 32 + lkc * 8;
#pragma unroll
    for (int jg = 0; jg < 8; ++jg) {
      int j = jg * 16 + lrow;
      int idx = j * 128 + (kb ^ ((j & 7) << 3));
      bf16x8 bh = *(const bf16x8*)(&Wl[0][idx]);
      bf16x8 bl = *(const bf16x8*)(&Wl[1][idx]);
      acc[jg] = __builtin_amdgcn_mfma_f32_16x16x32_bf16(ahH[ks], bh, acc[jg], 0, 0, 0);
      acc[jg] = __builtin_amdgcn_mfma_f32_16x16x32_bf16(ahH[ks], bl, acc[jg], 0, 0, 0);
      acc[jg] = __builtin_amdgcn_mfma_f32_16x16x32_bf16(ahL[ks], bh, acc[jg], 0, 0, 0);
    }
  }
  float s0[8], s1[8], s2[8], s3[8];
  if (STATS) {
#pragma unroll
    for (int jg = 0; jg < 8; ++jg) { s0[jg] = 0.f; s1[jg] = 0.f; s2[jg] = 0.f; s3[jg] = 0.f; }
  }
  float wsr[4], wor[4];
  if (STATS) {
#pragma unroll
    for (int q = 0; q < 4; ++q) {
      int n = v * kO + wr + lkc * 4 + q;
      wsr[q] = (float)cnt_s[n]; wor[q] = (float)cnt_o[n];
    }
  }
#pragma unroll
  for (int jg = 0; jg < 8; ++jg) {
    int col = jg * 16 + lrow;
    float bcol = bias2[col];
#pragma unroll
    for (int q = 0; q < 4; ++q) {
      int row = wr + lkc * 4 + q;
      size_t n = (size_t)v * kO + row;
      float vv = acc[jg][q] + bcol;
      if (resid) vv += resid[n * kD + col];
      Y[n * kD + col] = vv;
      if (STATS) {
        s0[jg] += wsr[q] * vv; s1[jg] += wsr[q] * vv * vv;
        s2[jg] += wor[q] * vv; s3[jg] += wor[q] * vv * vv;
      }
    }
  }
  if (STATS) {
    __syncthreads();  // W2 consumed; reuse Wl[0..1] as red [4][32][128] f32
    float* red4 = (float*)Wl[0];
#pragma unroll
    for (int jg = 0; jg < 8; ++jg) {
      int col = jg * 16 + lrow;
      red4[0 * 4096 + slot * 128 + col] = s0[jg];
      red4[1 * 4096 + slot * 128 + col] = s1[jg];
      red4[2 * 4096 + slot * 128 + col] = s2[jg];
      red4[3 * 4096 + slot * 128 + col] = s3[jg];
    }
    __syncthreads();
    if (t < 128) {
#pragma unroll
      for (int st = 0; st < 4; ++st) {
        float s = 0.f;
#pragma unroll
        for (int g = 0; g < 32; ++g) s += red4[st * 4096 + g * 128 + t];
        p1out[((size_t)v * 4 + st) * 128 + t] = s;
      }
    }
  }
}

extern "C" void kernel_launch(void* const* d_in, const int* in_sizes, int n_in,
                              void* d_out, int out_size, void* d_ws, size_t ws_size,
                              hipStream_t stream) {
  (void)in_sizes; (void)n_in; (void)out_size; (void)ws_size;
  const float* obj = (const float*)d_in[0];
  const unsigned int* ew = (const unsigned int*)d_in[1];
  const float* prm[2][8];
  for (int u = 0; u < 2; ++u)
    for (int p = 0; p < 8; ++p) prm[u][p] = (const float*)d_in[2 + u * 8 + p];
  // prm[u]: 0=g1 1=b1 2=W1 3=lb1 4=g2 5=b2 6=W2 7=lb2

  char* ws = (char*)d_ws;
  size_t off = 0;
  auto carve = [&](size_t bytes) -> char* {
    char* p = ws + off;
    off = (off + bytes + 255) & ~(size_t)255;
    return p;
  };
  int* cnt_s = (int*)carve((size_t)kN * 4);
  int* cnt_o = (int*)carve((size_t)kN * 4);
  unsigned short* Au16 = (unsigned short*)carve((size_t)kV * 16384 * 2);
  float* p1 = (float*)carve((size_t)256 * 4 * 128 * 4);
  float* p2 = (float*)carve((size_t)kV * 2 * 128 * 4);
  float* coef1 = (float*)carve(512 * 4);
  unsigned short *w1img[2], *w2img[2];
  for (int u = 0; u < 2; ++u) {
    w1img[u] = (unsigned short*)carve((size_t)4 * 16384 * 2);  // 128 KB
    w2img[u] = (unsigned short*)carve((size_t)2 * 16384 * 2);  // 64 KB
  }
  float* x2 = (float*)carve((size_t)kN * kD * 4);
  float* outp = (float*)d_out;

  k_init<<<288, 256, 0, stream>>>(ew, obj, cnt_s, cnt_o, Au16, p1,
                                  prm[0][2], prm[0][6], prm[1][2], prm[1][6],
                                  w1img[0], w2img[0], w1img[1], w2img[1]);

  // ---- unit 0 (cooperative) ----
  k_fin1<<<256, 256, 0, stream>>>(p1, prm[0][0], prm[0][1], coef1);
  {
    const float* X = obj;
    const unsigned short *wi = w1img[0], *w2i = w2img[0];
    const float *c1 = coef1;
    const unsigned short* Au = Au16;
    const int *cs = cnt_s, *co = cnt_o;
    const float *l1 = prm[0][3], *g2p = prm[0][4], *b2p = prm[0][5], *bi2 = prm[0][7];
    const float* rs = nullptr;
    float *p2p = p2, *Yp = x2, *p1p = p1;
    void* args[] = {(void*)&X, (void*)&wi, (void*)&w2i, (void*)&c1, (void*)&Au,
                    (void*)&cs, (void*)&co, (void*)&l1, (void*)&g2p, (void*)&b2p,
                    (void*)&bi2, (void*)&rs, (void*)&p2p, (void*)&Yp, (void*)&p1p};
    hipLaunchCooperativeKernel((const void*)k_unit<1>, dim3(kV), dim3(512),
                               args, 0, stream);
  }
  // ---- unit 1 (cooperative) ----
  k_fin1<<<256, 256, 0, stream>>>(p1, prm[1][0], prm[1][1], coef1);
  {
    const float* X = x2;
    const unsigned short *wi = w1img[1], *w2i = w2img[1];
    const float *c1 = coef1;
    const unsigned short* Au = Au16;
    const int *cs = cnt_s, *co = cnt_o;
    const float *l1 = prm[1][3], *g2p = prm[1][4], *b2p = prm[1][5], *bi2 = prm[1][7];
    const float* rs = obj;
    float *p2p = p2, *Yp = outp, *p1p = p1;
    void* args[] = {(void*)&X, (void*)&wi, (void*)&w2i, (void*)&c1, (void*)&Au,
                    (void*)&cs, (void*)&co, (void*)&l1, (void*)&g2p, (void*)&b2p,
                    (void*)&bi2, (void*)&rs, (void*)&p2p, (void*)&Yp, (void*)&p1p};
    hipLaunchCooperativeKernel((const void*)k_unit<0>, dim3(kV), dim3(512),
                               args, 0, stream);
  }
}